// Round 1
// baseline (1625.751 us; speedup 1.0000x reference)
//
#include <hip/hip_runtime.h>
#include <math.h>

#define NB 4
#define SEQ 4096
#define DM 1024
#define NG 4
#define DI 512
#define NQS 1024
#define NKS 512
#define NHD 8
#define DHD 64

typedef unsigned int u32;
typedef unsigned short u16;

__device__ __forceinline__ float bf2f(u16 u) { return __uint_as_float(((u32)u) << 16); }
__device__ __forceinline__ u16 f2bf(float f) {
  u32 u = __float_as_uint(f);
  u32 r = (u + 0x7FFFu + ((u >> 16) & 1u)) >> 16;
  return (u16)r;
}

// ---------------- router: logits[b][g][n] for q and kv ----------------
__global__ __launch_bounds__(256) void router_kernel(
    const float* __restrict__ x, const float* __restrict__ wqr,
    const float* __restrict__ wkvr, float* __restrict__ qlog,
    float* __restrict__ kvlog) {
  __shared__ float wsm[8192];
  int tid = threadIdx.x;
  for (int k = tid; k < 8192; k += 256)
    wsm[k] = (k < 4096) ? wqr[k] : wkvr[k - 4096];
  __syncthreads();
  int widx = blockIdx.x * 4 + (tid >> 6);  // 0..16383
  int lane = tid & 63;
  int b = widx >> 12, tok = widx & 4095;
  const float4* xr = (const float4*)(x + ((size_t)(b * SEQ + tok)) * DM);
  float4 xv[4];
#pragma unroll
  for (int i = 0; i < 4; i++) xv[i] = xr[i * 64 + lane];
  float accs[8];
#pragma unroll
  for (int r = 0; r < 8; r++) {
    const float4* wr = (const float4*)(wsm + r * 1024);
    float a = 0.f;
#pragma unroll
    for (int i = 0; i < 4; i++) {
      float4 w4 = wr[i * 64 + lane];
      a += xv[i].x * w4.x + xv[i].y * w4.y + xv[i].z * w4.z + xv[i].w * w4.w;
    }
    accs[r] = a;
  }
#pragma unroll
  for (int r = 0; r < 8; r++) {
    float a = accs[r];
#pragma unroll
    for (int off = 32; off >= 1; off >>= 1) a += __shfl_xor(a, off);
    if (lane == 0) {
      if (r < 4) qlog[((b << 2) | r) * SEQ + tok] = a;
      else kvlog[((b << 2) | (r - 4)) * SEQ + tok] = a;
    }
  }
}

// ---------------- top-k radix select per (b,g) ----------------
__global__ __launch_bounds__(256) void topk_kernel(
    const float* __restrict__ logits, int K, int* __restrict__ out_idx,
    float* __restrict__ out_score, float* __restrict__ counts) {
  __shared__ u32 keys[4096];
  __shared__ int eqlist[2048];
  __shared__ int scnt[4];
  __shared__ int s_gt, s_eq;
  int bg = blockIdx.x;
  int tid = threadIdx.x;
  const float* L = logits + bg * 4096;
  for (int e = tid; e < 4096; e += 256) {
    u32 u = __float_as_uint(L[e]);
    keys[e] = (u >> 31) ? ~u : (u | 0x80000000u);
  }
  if (tid == 0) { s_gt = 0; s_eq = 0; }
  __syncthreads();
  u32 prefix = 0;
  int remaining = K;
  for (int bit = 31; bit >= 0; --bit) {
    u32 want = prefix | (1u << bit);
    u32 mask = ~((1u << bit) - 1u);
    int c = 0;
    for (int e = tid; e < 4096; e += 256) c += ((keys[e] & mask) == want) ? 1 : 0;
#pragma unroll
    for (int off = 32; off >= 1; off >>= 1) c += __shfl_xor(c, off);
    if ((tid & 63) == 0) scnt[tid >> 6] = c;
    __syncthreads();
    int total = scnt[0] + scnt[1] + scnt[2] + scnt[3];
    if (total >= remaining) prefix = want;
    else remaining -= total;
    __syncthreads();
  }
  u32 T = prefix;
  for (int e = tid; e < 4096; e += 256) {
    u32 k = keys[e];
    if (k > T) {
      int pos = atomicAdd(&s_gt, 1);
      out_idx[bg * K + pos] = e;
      float v = L[e];
      out_score[bg * K + pos] = 1.0f / (1.0f + __expf(-v));
      if (counts) atomicAdd(&counts[(bg >> 2) * SEQ + e], 1.0f);
    } else if (k == T) {
      int p = atomicAdd(&s_eq, 1);
      if (p < 2048) eqlist[p] = e;
    }
  }
  __syncthreads();
  int gt = s_gt;
  int eq = min(s_eq, 2048);
  int need = K - gt;
  for (int i = tid; i < eq; i += 256) {
    int my = eqlist[i];
    int rank = 0;
    for (int j = 0; j < eq; j++) rank += (eqlist[j] < my) ? 1 : 0;
    if (rank < need) {
      int pos = gt + rank;
      out_idx[bg * K + pos] = my;
      float v = L[my];
      out_score[bg * K + pos] = 1.0f / (1.0f + __expf(-v));
      if (counts) atomicAdd(&counts[(bg >> 2) * SEQ + my], 1.0f);
    }
  }
}

// ---------------- q projection: C[1024,512] = gather(x) @ w_q^T ----------------
__global__ __launch_bounds__(256) void gemm_qproj(
    const float* __restrict__ x, const int* __restrict__ qidx,
    const float* __restrict__ wq, u16* __restrict__ qbuf) {
  int bg = blockIdx.z, b = bg >> 2, g = bg & 3;
  int row0 = blockIdx.y * 64, col0 = blockIdx.x * 64;
  __shared__ float As[32][68], Bs[32][68];
  __shared__ int ridx[64];
  int tid = threadIdx.x;
  if (tid < 64) ridx[tid] = qidx[bg * NQS + row0 + tid];
  __syncthreads();
  int lr = tid >> 2, ks = (tid & 3) * 8;
  int tx = tid & 15, ty = tid >> 4;
  float acc[4][4] = {};
  const float* Ab = x + (size_t)(b * SEQ + ridx[lr]) * DM + ks;
  const float* Bb = wq + (size_t)g * DI * DM + (size_t)(col0 + lr) * DM + ks;
  for (int k0 = 0; k0 < 1024; k0 += 32) {
    float4 a0 = *(const float4*)(Ab + k0);
    float4 a1 = *(const float4*)(Ab + k0 + 4);
    float4 b0 = *(const float4*)(Bb + k0);
    float4 b1 = *(const float4*)(Bb + k0 + 4);
    As[ks + 0][lr] = a0.x; As[ks + 1][lr] = a0.y; As[ks + 2][lr] = a0.z; As[ks + 3][lr] = a0.w;
    As[ks + 4][lr] = a1.x; As[ks + 5][lr] = a1.y; As[ks + 6][lr] = a1.z; As[ks + 7][lr] = a1.w;
    Bs[ks + 0][lr] = b0.x; Bs[ks + 1][lr] = b0.y; Bs[ks + 2][lr] = b0.z; Bs[ks + 3][lr] = b0.w;
    Bs[ks + 4][lr] = b1.x; Bs[ks + 5][lr] = b1.y; Bs[ks + 6][lr] = b1.z; Bs[ks + 7][lr] = b1.w;
    __syncthreads();
#pragma unroll 8
    for (int kk = 0; kk < 32; kk++) {
      float4 av = *(const float4*)&As[kk][ty * 4];
      float4 bv = *(const float4*)&Bs[kk][tx * 4];
      acc[0][0] += av.x * bv.x; acc[0][1] += av.x * bv.y; acc[0][2] += av.x * bv.z; acc[0][3] += av.x * bv.w;
      acc[1][0] += av.y * bv.x; acc[1][1] += av.y * bv.y; acc[1][2] += av.y * bv.z; acc[1][3] += av.y * bv.w;
      acc[2][0] += av.z * bv.x; acc[2][1] += av.z * bv.y; acc[2][2] += av.z * bv.z; acc[2][3] += av.z * bv.w;
      acc[3][0] += av.w * bv.x; acc[3][1] += av.w * bv.y; acc[3][2] += av.w * bv.z; acc[3][3] += av.w * bv.w;
    }
    __syncthreads();
  }
#pragma unroll
  for (int i = 0; i < 4; i++) {
    ushort4 st;
    st.x = f2bf(acc[i][0]); st.y = f2bf(acc[i][1]);
    st.z = f2bf(acc[i][2]); st.w = f2bf(acc[i][3]);
    *(ushort4*)(qbuf + ((size_t)bg * NQS + row0 + ty * 4 + i) * DI + col0 + tx * 4) = st;
  }
}

// ---------------- kv projection: C[512,1024] = gather(x) @ w_kv^T, v-cols scaled ----------------
__global__ __launch_bounds__(256) void gemm_kvproj(
    const float* __restrict__ x, const int* __restrict__ kvidx,
    const float* __restrict__ wkv, const float* __restrict__ kvscore,
    u16* __restrict__ kvbuf) {
  int bg = blockIdx.z, b = bg >> 2, g = bg & 3;
  int row0 = blockIdx.y * 64, col0 = blockIdx.x * 64;
  __shared__ float As[32][68], Bs[32][68];
  __shared__ int ridx[64];
  int tid = threadIdx.x;
  if (tid < 64) ridx[tid] = kvidx[bg * NKS + row0 + tid];
  __syncthreads();
  int lr = tid >> 2, ks = (tid & 3) * 8;
  int tx = tid & 15, ty = tid >> 4;
  float acc[4][4] = {};
  const float* Ab = x + (size_t)(b * SEQ + ridx[lr]) * DM + ks;
  const float* Bb = wkv + (size_t)g * (2 * DI) * DM + (size_t)(col0 + lr) * DM + ks;
  for (int k0 = 0; k0 < 1024; k0 += 32) {
    float4 a0 = *(const float4*)(Ab + k0);
    float4 a1 = *(const float4*)(Ab + k0 + 4);
    float4 b0 = *(const float4*)(Bb + k0);
    float4 b1 = *(const float4*)(Bb + k0 + 4);
    As[ks + 0][lr] = a0.x; As[ks + 1][lr] = a0.y; As[ks + 2][lr] = a0.z; As[ks + 3][lr] = a0.w;
    As[ks + 4][lr] = a1.x; As[ks + 5][lr] = a1.y; As[ks + 6][lr] = a1.z; As[ks + 7][lr] = a1.w;
    Bs[ks + 0][lr] = b0.x; Bs[ks + 1][lr] = b0.y; Bs[ks + 2][lr] = b0.z; Bs[ks + 3][lr] = b0.w;
    Bs[ks + 4][lr] = b1.x; Bs[ks + 5][lr] = b1.y; Bs[ks + 6][lr] = b1.z; Bs[ks + 7][lr] = b1.w;
    __syncthreads();
#pragma unroll 8
    for (int kk = 0; kk < 32; kk++) {
      float4 av = *(const float4*)&As[kk][ty * 4];
      float4 bv = *(const float4*)&Bs[kk][tx * 4];
      acc[0][0] += av.x * bv.x; acc[0][1] += av.x * bv.y; acc[0][2] += av.x * bv.z; acc[0][3] += av.x * bv.w;
      acc[1][0] += av.y * bv.x; acc[1][1] += av.y * bv.y; acc[1][2] += av.y * bv.z; acc[1][3] += av.y * bv.w;
      acc[2][0] += av.z * bv.x; acc[2][1] += av.z * bv.y; acc[2][2] += av.z * bv.z; acc[2][3] += av.z * bv.w;
      acc[3][0] += av.w * bv.x; acc[3][1] += av.w * bv.y; acc[3][2] += av.w * bv.z; acc[3][3] += av.w * bv.w;
    }
    __syncthreads();
  }
  bool isv = (col0 >= DI);  // whole 64-col tile is in v-part or k-part
#pragma unroll
  for (int i = 0; i < 4; i++) {
    int rowg = row0 + ty * 4 + i;
    float sc = isv ? kvscore[bg * NKS + rowg] : 1.0f;
    ushort4 st;
    st.x = f2bf(acc[i][0] * sc); st.y = f2bf(acc[i][1] * sc);
    st.z = f2bf(acc[i][2] * sc); st.w = f2bf(acc[i][3] * sc);
    *(ushort4*)(kvbuf + ((size_t)bg * NKS + rowg) * (2 * DI) + col0 + tx * 4) = st;
  }
}

// ---------------- attention: per (bg,h,16-query tile), 513 keys ----------------
__global__ __launch_bounds__(256) void attn_kernel(
    const u16* __restrict__ qbuf, const u16* __restrict__ kvbuf,
    const float* __restrict__ null_kv, u16* __restrict__ obuf) {
  int qt = blockIdx.x;  // 0..63
  int h = blockIdx.y;   // 0..7
  int bg = blockIdx.z;  // 0..15
  int g = bg & 3;
  int tid = threadIdx.x;
  __shared__ float Qs[16][68];
  __shared__ float KV[64][68];
  __shared__ float Sd[16][522];
  __shared__ float red[16][17];
  __shared__ float rowm[16], invl[16];
  int q = tid >> 4;   // 0..15
  int tx = tid & 15;  // 0..15
  int qg = qt * 16 + q;
  {
    int dh = tx * 4;
    const u16* qp = qbuf + ((size_t)bg * NQS + qg) * DI + h * DHD + dh;
    uint2 u = *(const uint2*)qp;
    Qs[q][dh + 0] = bf2f((u16)(u.x & 0xffff)); Qs[q][dh + 1] = bf2f((u16)(u.x >> 16));
    Qs[q][dh + 2] = bf2f((u16)(u.y & 0xffff)); Qs[q][dh + 3] = bf2f((u16)(u.y >> 16));
  }
  int jl = tid >> 2;           // loader: key row 0..63
  int dh0l = (tid & 3) * 16;   // loader: dh segment
  // Phase 1: scores
  for (int c = 0; c < 9; c++) {
    int jglob = c * 64 + jl;
    if (jglob < 513) {
      if (jglob == 0) {
#pragma unroll
        for (int i = 0; i < 16; i++)
          KV[dh0l + i][jl] = null_kv[((0 * NG + g) * NHD + h) * DHD + dh0l + i];
      } else {
        const u16* kp = kvbuf + ((size_t)bg * NKS + (jglob - 1)) * (2 * DI) + h * DHD + dh0l;
#pragma unroll
        for (int i = 0; i < 16; i++) KV[dh0l + i][jl] = bf2f(kp[i]);
      }
    } else {
#pragma unroll
      for (int i = 0; i < 16; i++) KV[dh0l + i][jl] = 0.f;
    }
    __syncthreads();
    float4 a = {0.f, 0.f, 0.f, 0.f};
    int j0 = tx * 4;
#pragma unroll 8
    for (int dh = 0; dh < 64; dh++) {
      float qv = Qs[q][dh];
      float4 k4 = *(const float4*)&KV[dh][j0];
      a.x += qv * k4.x; a.y += qv * k4.y; a.z += qv * k4.z; a.w += qv * k4.w;
    }
    int jg = c * 64 + j0;
    if (jg + 0 < 513) Sd[q][jg + 0] = a.x * 0.125f;
    if (jg + 1 < 513) Sd[q][jg + 1] = a.y * 0.125f;
    if (jg + 2 < 513) Sd[q][jg + 2] = a.z * 0.125f;
    if (jg + 3 < 513) Sd[q][jg + 3] = a.w * 0.125f;
    __syncthreads();
  }
  // Phase 2: softmax (unnormalized exp; 1/l applied at end)
  {
    float m = -INFINITY;
    for (int j = tx; j < 513; j += 16) m = fmaxf(m, Sd[q][j]);
    red[q][tx] = m;
    __syncthreads();
    if (tx == 0) {
      float mm = red[q][0];
#pragma unroll
      for (int i = 1; i < 16; i++) mm = fmaxf(mm, red[q][i]);
      rowm[q] = mm;
    }
    __syncthreads();
    float mm = rowm[q];
    float s = 0.f;
    for (int j = tx; j < 513; j += 16) {
      float e = __expf(Sd[q][j] - mm);
      Sd[q][j] = e;
      s += e;
    }
    red[q][tx] = s;
    __syncthreads();
    if (tx == 0) {
      float ss = 0.f;
#pragma unroll
      for (int i = 0; i < 16; i++) ss += red[q][i];
      invl[q] = 1.0f / ss;
    }
    __syncthreads();
  }
  // Phase 3: O = P @ V
  float4 acc = {0.f, 0.f, 0.f, 0.f};
  int dh0 = tx * 4;
  for (int c = 0; c < 9; c++) {
    int jglob = c * 64 + jl;
    if (jglob < 513) {
      if (jglob == 0) {
#pragma unroll
        for (int i = 0; i < 16; i++)
          KV[jl][dh0l + i] = null_kv[((1 * NG + g) * NHD + h) * DHD + dh0l + i];
      } else {
        const u16* vp = kvbuf + ((size_t)bg * NKS + (jglob - 1)) * (2 * DI) + DI + h * DHD + dh0l;
#pragma unroll
        for (int i = 0; i < 16; i++) KV[jl][dh0l + i] = bf2f(vp[i]);
      }
    }
    __syncthreads();
    int jmax = min(64, 513 - c * 64);
    for (int j = 0; j < jmax; j++) {
      float p = Sd[q][c * 64 + j];
      float4 v4 = *(const float4*)&KV[j][dh0];
      acc.x += p * v4.x; acc.y += p * v4.y; acc.z += p * v4.z; acc.w += p * v4.w;
    }
    __syncthreads();
  }
  float il = invl[q];
  ushort4 st;
  st.x = f2bf(acc.x * il); st.y = f2bf(acc.y * il);
  st.z = f2bf(acc.z * il); st.w = f2bf(acc.w * il);
  *(ushort4*)(obuf + ((size_t)bg * NQS + qg) * DI + h * DHD + dh0) = st;
}

// ---------------- out projection + scaled scatter-add ----------------
__global__ __launch_bounds__(256) void gemm_outproj(
    const u16* __restrict__ obuf, const float* __restrict__ wout,
    const int* __restrict__ qidx, const float* __restrict__ qscore,
    float* __restrict__ dout) {
  int bg = blockIdx.z, b = bg >> 2, g = bg & 3;
  int row0 = blockIdx.y * 64, col0 = blockIdx.x * 64;
  __shared__ float As[32][68], Bs[32][68];
  int tid = threadIdx.x;
  int lr = tid >> 2, ks = (tid & 3) * 8;
  int tx = tid & 15, ty = tid >> 4;
  float acc[4][4] = {};
  const u16* Ab = obuf + ((size_t)bg * NQS + row0 + lr) * DI + ks;
  const float* Bb = wout + (size_t)g * DM * DI + (size_t)(col0 + lr) * DI + ks;
  for (int k0 = 0; k0 < 512; k0 += 32) {
    uint4 ua = *(const uint4*)(Ab + k0);
    float4 b0 = *(const float4*)(Bb + k0);
    float4 b1 = *(const float4*)(Bb + k0 + 4);
    As[ks + 0][lr] = bf2f((u16)(ua.x & 0xffff)); As[ks + 1][lr] = bf2f((u16)(ua.x >> 16));
    As[ks + 2][lr] = bf2f((u16)(ua.y & 0xffff)); As[ks + 3][lr] = bf2f((u16)(ua.y >> 16));
    As[ks + 4][lr] = bf2f((u16)(ua.z & 0xffff)); As[ks + 5][lr] = bf2f((u16)(ua.z >> 16));
    As[ks + 6][lr] = bf2f((u16)(ua.w & 0xffff)); As[ks + 7][lr] = bf2f((u16)(ua.w >> 16));
    Bs[ks + 0][lr] = b0.x; Bs[ks + 1][lr] = b0.y; Bs[ks + 2][lr] = b0.z; Bs[ks + 3][lr] = b0.w;
    Bs[ks + 4][lr] = b1.x; Bs[ks + 5][lr] = b1.y; Bs[ks + 6][lr] = b1.z; Bs[ks + 7][lr] = b1.w;
    __syncthreads();
#pragma unroll 8
    for (int kk = 0; kk < 32; kk++) {
      float4 av = *(const float4*)&As[kk][ty * 4];
      float4 bv = *(const float4*)&Bs[kk][tx * 4];
      acc[0][0] += av.x * bv.x; acc[0][1] += av.x * bv.y; acc[0][2] += av.x * bv.z; acc[0][3] += av.x * bv.w;
      acc[1][0] += av.y * bv.x; acc[1][1] += av.y * bv.y; acc[1][2] += av.y * bv.z; acc[1][3] += av.y * bv.w;
      acc[2][0] += av.z * bv.x; acc[2][1] += av.z * bv.y; acc[2][2] += av.z * bv.z; acc[2][3] += av.z * bv.w;
      acc[3][0] += av.w * bv.x; acc[3][1] += av.w * bv.y; acc[3][2] += av.w * bv.z; acc[3][3] += av.w * bv.w;
    }
    __syncthreads();
  }
#pragma unroll
  for (int i = 0; i < 4; i++) {
    int rowg = row0 + ty * 4 + i;
    float sc = qscore[bg * NQS + rowg];
    int tok = qidx[bg * NQS + rowg];
    float* orow = dout + ((size_t)b * SEQ + tok) * DM + col0 + tx * 4;
    atomicAdd(&orow[0], acc[i][0] * sc);
    atomicAdd(&orow[1], acc[i][1] * sc);
    atomicAdd(&orow[2], acc[i][2] * sc);
    atomicAdd(&orow[3], acc[i][3] * sc);
  }
}

// ---------------- finalize: mean + null-token fill ----------------
__global__ __launch_bounds__(256) void finalize_kernel(
    float* __restrict__ dout, const float* __restrict__ counts,
    const float* __restrict__ null_token) {
  int qd = blockIdx.x * 256 + threadIdx.x;  // quad index
  int row = qd >> 8;
  int c4 = qd & 255;
  float cnt = counts[row];
  float4* p = (float4*)dout + qd;
  if (cnt > 0.f) {
    float4 v = *p;
    float inv = 1.0f / cnt;
    v.x *= inv; v.y *= inv; v.z *= inv; v.w *= inv;
    *p = v;
  } else {
    *p = ((const float4*)null_token)[c4];
  }
}

extern "C" void kernel_launch(void* const* d_in, const int* in_sizes, int n_in,
                              void* d_out, int out_size, void* d_ws, size_t ws_size,
                              hipStream_t stream) {
  const float* x = (const float*)d_in[0];
  const float* wqr = (const float*)d_in[1];
  const float* wkvr = (const float*)d_in[2];
  const float* wq = (const float*)d_in[3];
  const float* wkv = (const float*)d_in[4];
  const float* wout = (const float*)d_in[5];
  const float* nullkv = (const float*)d_in[6];
  const float* nulltok = (const float*)d_in[7];
  float* out = (float*)d_out;
  char* ws = (char*)d_ws;
  // workspace layout (bytes)
  float* qlog = (float*)(ws + 0);                 // 262144
  float* kvlog = (float*)(ws + 262144);           // 262144
  int* qidx = (int*)(ws + 524288);                // 65536
  int* kvidx = (int*)(ws + 589824);               // 32768
  float* qscore = (float*)(ws + 622592);          // 65536
  float* kvscore = (float*)(ws + 688128);         // 32768
  float* counts = (float*)(ws + 720896);          // 65536
  u16* qbuf = (u16*)(ws + 786432);                // 16 MB bf16 [16][1024][512]
  u16* kvbuf = (u16*)(ws + 786432 + 16777216);    // 16 MB bf16 [16][512][1024]
  u16* obuf = (u16*)(ws + 786432 + 33554432);     // 16 MB bf16 [16][1024][512]

  hipMemsetAsync(counts, 0, 65536, stream);
  hipMemsetAsync(out, 0, (size_t)NB * SEQ * DM * 4, stream);
  router_kernel<<<4096, 256, 0, stream>>>(x, wqr, wkvr, qlog, kvlog);
  topk_kernel<<<16, 256, 0, stream>>>(qlog, NQS, qidx, qscore, counts);
  topk_kernel<<<16, 256, 0, stream>>>(kvlog, NKS, kvidx, kvscore, nullptr);
  gemm_qproj<<<dim3(8, 16, 16), 256, 0, stream>>>(x, qidx, wq, qbuf);
  gemm_kvproj<<<dim3(16, 8, 16), 256, 0, stream>>>(x, kvidx, wkv, kvscore, kvbuf);
  attn_kernel<<<dim3(64, 8, 16), 256, 0, stream>>>(qbuf, kvbuf, nullkv, obuf);
  gemm_outproj<<<dim3(16, 16, 16), 256, 0, stream>>>(obuf, wout, qidx, qscore, out);
  finalize_kernel<<<16384, 256, 0, stream>>>(out, counts, nulltok);
}

// Round 2
// 1097.902 us; speedup vs baseline: 1.4808x; 1.4808x over previous
//
#include <hip/hip_runtime.h>
#include <math.h>

#define NB 4
#define SEQ 4096
#define DM 1024
#define NG 4
#define DI 512
#define NQS 1024
#define NKS 512
#define NHD 8
#define DHD 64
#define VTS 520  // vtbuf row stride (513 cols used, padded)

typedef unsigned int u32;
typedef unsigned short u16;
typedef __bf16 bf16x8 __attribute__((ext_vector_type(8)));
typedef float f32x4 __attribute__((ext_vector_type(4)));

__device__ __forceinline__ float bf2f(u16 u) { return __uint_as_float(((u32)u) << 16); }
__device__ __forceinline__ u16 f2bf(float f) {
  u32 u = __float_as_uint(f);
  u32 r = (u + 0x7FFFu + ((u >> 16) & 1u)) >> 16;
  return (u16)r;
}

// ---------------- router: logits[b][g][n] for q and kv ----------------
__global__ __launch_bounds__(256) void router_kernel(
    const float* __restrict__ x, const float* __restrict__ wqr,
    const float* __restrict__ wkvr, float* __restrict__ qlog,
    float* __restrict__ kvlog) {
  __shared__ float wsm[8192];
  int tid = threadIdx.x;
  for (int k = tid; k < 8192; k += 256)
    wsm[k] = (k < 4096) ? wqr[k] : wkvr[k - 4096];
  __syncthreads();
  int widx = blockIdx.x * 4 + (tid >> 6);
  int lane = tid & 63;
  int b = widx >> 12, tok = widx & 4095;
  const float4* xr = (const float4*)(x + ((size_t)(b * SEQ + tok)) * DM);
  float4 xv[4];
#pragma unroll
  for (int i = 0; i < 4; i++) xv[i] = xr[i * 64 + lane];
  float accs[8];
#pragma unroll
  for (int r = 0; r < 8; r++) {
    const float4* wr = (const float4*)(wsm + r * 1024);
    float a = 0.f;
#pragma unroll
    for (int i = 0; i < 4; i++) {
      float4 w4 = wr[i * 64 + lane];
      a += xv[i].x * w4.x + xv[i].y * w4.y + xv[i].z * w4.z + xv[i].w * w4.w;
    }
    accs[r] = a;
  }
#pragma unroll
  for (int r = 0; r < 8; r++) {
    float a = accs[r];
#pragma unroll
    for (int off = 32; off >= 1; off >>= 1) a += __shfl_xor(a, off);
    if (lane == 0) {
      if (r < 4) qlog[((b << 2) | r) * SEQ + tok] = a;
      else kvlog[((b << 2) | (r - 4)) * SEQ + tok] = a;
    }
  }
}

// ---------------- top-k radix select per (b,g) ----------------
__global__ __launch_bounds__(256) void topk_kernel(
    const float* __restrict__ logits, int K, int* __restrict__ out_idx,
    float* __restrict__ out_score, float* __restrict__ counts) {
  __shared__ u32 keys[4096];
  __shared__ int eqlist[2048];
  __shared__ int scnt[4];
  __shared__ int s_gt, s_eq;
  int bg = blockIdx.x;
  int tid = threadIdx.x;
  const float* L = logits + bg * 4096;
  for (int e = tid; e < 4096; e += 256) {
    u32 u = __float_as_uint(L[e]);
    keys[e] = (u >> 31) ? ~u : (u | 0x80000000u);
  }
  if (tid == 0) { s_gt = 0; s_eq = 0; }
  __syncthreads();
  u32 prefix = 0;
  int remaining = K;
  for (int bit = 31; bit >= 0; --bit) {
    u32 want = prefix | (1u << bit);
    u32 mask = ~((1u << bit) - 1u);
    int c = 0;
    for (int e = tid; e < 4096; e += 256) c += ((keys[e] & mask) == want) ? 1 : 0;
#pragma unroll
    for (int off = 32; off >= 1; off >>= 1) c += __shfl_xor(c, off);
    if ((tid & 63) == 0) scnt[tid >> 6] = c;
    __syncthreads();
    int total = scnt[0] + scnt[1] + scnt[2] + scnt[3];
    if (total >= remaining) prefix = want;
    else remaining -= total;
    __syncthreads();
  }
  u32 T = prefix;
  for (int e = tid; e < 4096; e += 256) {
    u32 k = keys[e];
    if (k > T) {
      int pos = atomicAdd(&s_gt, 1);
      out_idx[bg * K + pos] = e;
      float v = L[e];
      out_score[bg * K + pos] = 1.0f / (1.0f + __expf(-v));
      if (counts) atomicAdd(&counts[(bg >> 2) * SEQ + e], 1.0f);
    } else if (k == T) {
      int p = atomicAdd(&s_eq, 1);
      if (p < 2048) eqlist[p] = e;
    }
  }
  __syncthreads();
  int gt = s_gt;
  int eq = min(s_eq, 2048);
  int need = K - gt;
  for (int i = tid; i < eq; i += 256) {
    int my = eqlist[i];
    int rank = 0;
    for (int j = 0; j < eq; j++) rank += (eqlist[j] < my) ? 1 : 0;
    if (rank < need) {
      int pos = gt + rank;
      out_idx[bg * K + pos] = my;
      float v = L[my];
      out_score[bg * K + pos] = 1.0f / (1.0f + __expf(-v));
      if (counts) atomicAdd(&counts[(bg >> 2) * SEQ + my], 1.0f);
    }
  }
}

// ---------------- q projection: C[1024,512] = gather(x) @ w_q^T ----------------
__global__ __launch_bounds__(256) void gemm_qproj(
    const float* __restrict__ x, const int* __restrict__ qidx,
    const float* __restrict__ wq, u16* __restrict__ qbuf) {
  int bg = blockIdx.z, b = bg >> 2, g = bg & 3;
  int row0 = blockIdx.y * 64, col0 = blockIdx.x * 64;
  __shared__ float As[32][68], Bs[32][68];
  __shared__ int ridx[64];
  int tid = threadIdx.x;
  if (tid < 64) ridx[tid] = qidx[bg * NQS + row0 + tid];
  __syncthreads();
  int lr = tid >> 2, ks = (tid & 3) * 8;
  int tx = tid & 15, ty = tid >> 4;
  float acc[4][4] = {};
  const float* Ab = x + (size_t)(b * SEQ + ridx[lr]) * DM + ks;
  const float* Bb = wq + (size_t)g * DI * DM + (size_t)(col0 + lr) * DM + ks;
  for (int k0 = 0; k0 < 1024; k0 += 32) {
    float4 a0 = *(const float4*)(Ab + k0);
    float4 a1 = *(const float4*)(Ab + k0 + 4);
    float4 b0 = *(const float4*)(Bb + k0);
    float4 b1 = *(const float4*)(Bb + k0 + 4);
    As[ks + 0][lr] = a0.x; As[ks + 1][lr] = a0.y; As[ks + 2][lr] = a0.z; As[ks + 3][lr] = a0.w;
    As[ks + 4][lr] = a1.x; As[ks + 5][lr] = a1.y; As[ks + 6][lr] = a1.z; As[ks + 7][lr] = a1.w;
    Bs[ks + 0][lr] = b0.x; Bs[ks + 1][lr] = b0.y; Bs[ks + 2][lr] = b0.z; Bs[ks + 3][lr] = b0.w;
    Bs[ks + 4][lr] = b1.x; Bs[ks + 5][lr] = b1.y; Bs[ks + 6][lr] = b1.z; Bs[ks + 7][lr] = b1.w;
    __syncthreads();
#pragma unroll 8
    for (int kk = 0; kk < 32; kk++) {
      float4 av = *(const float4*)&As[kk][ty * 4];
      float4 bv = *(const float4*)&Bs[kk][tx * 4];
      acc[0][0] += av.x * bv.x; acc[0][1] += av.x * bv.y; acc[0][2] += av.x * bv.z; acc[0][3] += av.x * bv.w;
      acc[1][0] += av.y * bv.x; acc[1][1] += av.y * bv.y; acc[1][2] += av.y * bv.z; acc[1][3] += av.y * bv.w;
      acc[2][0] += av.z * bv.x; acc[2][1] += av.z * bv.y; acc[2][2] += av.z * bv.z; acc[2][3] += av.z * bv.w;
      acc[3][0] += av.w * bv.x; acc[3][1] += av.w * bv.y; acc[3][2] += av.w * bv.z; acc[3][3] += av.w * bv.w;
    }
    __syncthreads();
  }
#pragma unroll
  for (int i = 0; i < 4; i++) {
    ushort4 st;
    st.x = f2bf(acc[i][0]); st.y = f2bf(acc[i][1]);
    st.z = f2bf(acc[i][2]); st.w = f2bf(acc[i][3]);
    *(ushort4*)(qbuf + ((size_t)bg * NQS + row0 + ty * 4 + i) * DI + col0 + tx * 4) = st;
  }
}

// ---------------- kv projection: K -> kbuf[bg][512][512], V^T -> vtbuf[bg][h][64][VTS] ----------------
__global__ __launch_bounds__(256) void gemm_kvproj(
    const float* __restrict__ x, const int* __restrict__ kvidx,
    const float* __restrict__ wkv, const float* __restrict__ kvscore,
    u16* __restrict__ kbuf, u16* __restrict__ vtbuf) {
  int bg = blockIdx.z, b = bg >> 2, g = bg & 3;
  int row0 = blockIdx.y * 64, col0 = blockIdx.x * 64;
  __shared__ float As[32][68], Bs[32][68];
  __shared__ int ridx[64];
  int tid = threadIdx.x;
  if (tid < 64) ridx[tid] = kvidx[bg * NKS + row0 + tid];
  __syncthreads();
  int lr = tid >> 2, ks = (tid & 3) * 8;
  int tx = tid & 15, ty = tid >> 4;
  float acc[4][4] = {};
  const float* Ab = x + (size_t)(b * SEQ + ridx[lr]) * DM + ks;
  const float* Bb = wkv + (size_t)g * (2 * DI) * DM + (size_t)(col0 + lr) * DM + ks;
  for (int k0 = 0; k0 < 1024; k0 += 32) {
    float4 a0 = *(const float4*)(Ab + k0);
    float4 a1 = *(const float4*)(Ab + k0 + 4);
    float4 b0 = *(const float4*)(Bb + k0);
    float4 b1 = *(const float4*)(Bb + k0 + 4);
    As[ks + 0][lr] = a0.x; As[ks + 1][lr] = a0.y; As[ks + 2][lr] = a0.z; As[ks + 3][lr] = a0.w;
    As[ks + 4][lr] = a1.x; As[ks + 5][lr] = a1.y; As[ks + 6][lr] = a1.z; As[ks + 7][lr] = a1.w;
    Bs[ks + 0][lr] = b0.x; Bs[ks + 1][lr] = b0.y; Bs[ks + 2][lr] = b0.z; Bs[ks + 3][lr] = b0.w;
    Bs[ks + 4][lr] = b1.x; Bs[ks + 5][lr] = b1.y; Bs[ks + 6][lr] = b1.z; Bs[ks + 7][lr] = b1.w;
    __syncthreads();
#pragma unroll 8
    for (int kk = 0; kk < 32; kk++) {
      float4 av = *(const float4*)&As[kk][ty * 4];
      float4 bv = *(const float4*)&Bs[kk][tx * 4];
      acc[0][0] += av.x * bv.x; acc[0][1] += av.x * bv.y; acc[0][2] += av.x * bv.z; acc[0][3] += av.x * bv.w;
      acc[1][0] += av.y * bv.x; acc[1][1] += av.y * bv.y; acc[1][2] += av.y * bv.z; acc[1][3] += av.y * bv.w;
      acc[2][0] += av.z * bv.x; acc[2][1] += av.z * bv.y; acc[2][2] += av.z * bv.z; acc[2][3] += av.z * bv.w;
      acc[3][0] += av.w * bv.x; acc[3][1] += av.w * bv.y; acc[3][2] += av.w * bv.z; acc[3][3] += av.w * bv.w;
    }
    __syncthreads();
  }
  if (col0 < DI) {
    // K tile: row-major store
#pragma unroll
    for (int i = 0; i < 4; i++) {
      int rowg = row0 + ty * 4 + i;
      ushort4 st;
      st.x = f2bf(acc[i][0]); st.y = f2bf(acc[i][1]);
      st.z = f2bf(acc[i][2]); st.w = f2bf(acc[i][3]);
      *(ushort4*)(kbuf + ((size_t)bg * NKS + rowg) * DI + col0 + tx * 4) = st;
    }
  } else {
    // V tile: scale by kv_score, store TRANSPOSED per head, col = key+1 (col 0 = null)
#pragma unroll
    for (int i = 0; i < 4; i++) {
      int rowg = row0 + ty * 4 + i;
      float sc = kvscore[bg * NKS + rowg];
#pragma unroll
      for (int e = 0; e < 4; e++) {
        int colg = col0 - DI + tx * 4 + e;  // 0..511
        int h = colg >> 6, d = colg & 63;
        vtbuf[(((size_t)bg * NHD + h) * DHD + d) * VTS + rowg + 1] = f2bf(acc[i][e] * sc);
      }
    }
  }
}

// ---------------- MFMA flash attention: block = (bg, h, 64 queries) ----------------
__global__ __launch_bounds__(256) void attn_mfma(
    const u16* __restrict__ qbuf, const u16* __restrict__ kbuf,
    const u16* __restrict__ vtbuf, const float* __restrict__ null_kv,
    u16* __restrict__ obuf) {
  int qt = blockIdx.x;  // 0..15 (tiles of 64 queries)
  int h = blockIdx.y;   // 0..7
  int bg = blockIdx.z;  // 0..15
  int g = bg & 3;
  int tid = threadIdx.x;
  int w = tid >> 6, lane = tid & 63;
  int col = lane & 15, quad = lane >> 4;

  __shared__ u16 Ks[128][72];      // K chunk, row-major [key][d], pad->2-way free
  __shared__ u16 Vts[64][136];     // V^T chunk [d][key]
  __shared__ u16 Ps[4][16][136];   // per-wave P (bf16), [m][key]

  // Q fragments (A-layout: A[m=lane&15][k=quad*8+j]), k0 = 0 / 32
  int q0 = qt * 64 + w * 16;
  const u16* qp = qbuf + ((size_t)bg * NQS + q0 + col) * DI + h * DHD + quad * 8;
  bf16x8 qa0 = *(const bf16x8*)qp;
  bf16x8 qa1 = *(const bf16x8*)(qp + 32);

  f32x4 oacc[4] = {};  // O[row=quad*4+r][d=t*16+col]
  float m_run[4], l_run[4];
#pragma unroll
  for (int r = 0; r < 4; r++) { m_run[r] = -3.0e38f; l_run[r] = 0.f; }

  for (int c = 0; c < 5; c++) {
    int base = c * 128;
    // ---- stage K chunk: 128 rows x 64 d; 2 threads/row ----
    {
      int r = tid >> 1, half = tid & 1;
      int j = base + r;
      uint4* dst = (uint4*)&Ks[r][half * 32];
      if (j >= 1 && j <= 512) {
        const uint4* src = (const uint4*)(kbuf + ((size_t)bg * NKS + (j - 1)) * DI + h * DHD + half * 32);
        dst[0] = src[0]; dst[1] = src[1]; dst[2] = src[2]; dst[3] = src[3];
      } else if (j == 0) {
        const float* nk = null_kv + ((0 * NG + g) * NHD + h) * DHD + half * 32;
#pragma unroll
        for (int i = 0; i < 32; i++) Ks[0][half * 32 + i] = f2bf(nk[i]);
      } else {
        uint4 z = {0, 0, 0, 0};
        dst[0] = z; dst[1] = z; dst[2] = z; dst[3] = z;
      }
    }
    // ---- stage Vt chunk: 64 rows x 128 cols; 4 threads/row ----
    {
      int d = tid >> 2, seg = tid & 3;
      const uint4* src = (const uint4*)(vtbuf + (((size_t)bg * NHD + h) * DHD + d) * VTS + base + seg * 32);
      uint4* dst = (uint4*)&Vts[d][seg * 32];
      dst[0] = src[0]; dst[1] = src[1]; dst[2] = src[2]; dst[3] = src[3];
      if (c == 0 && seg == 0)
        Vts[d][0] = f2bf(null_kv[((1 * NG + g) * NHD + h) * DHD + d]);
    }
    __syncthreads();

    // ---- S = Q K^T for this chunk: 8 col-tiles of 16 keys ----
    float sreg[8][4];
#pragma unroll
    for (int t = 0; t < 8; t++) {
      bf16x8 kb0 = *(const bf16x8*)&Ks[t * 16 + col][quad * 8];
      bf16x8 kb1 = *(const bf16x8*)&Ks[t * 16 + col][quad * 8 + 32];
      f32x4 s = {0.f, 0.f, 0.f, 0.f};
      s = __builtin_amdgcn_mfma_f32_16x16x32_bf16(qa0, kb0, s, 0, 0, 0);
      s = __builtin_amdgcn_mfma_f32_16x16x32_bf16(qa1, kb1, s, 0, 0, 0);
      int jg = base + t * 16 + col;
      float msk = (jg < 513) ? 0.125f : 0.f;
      float off = (jg < 513) ? 0.f : -3.0e38f;
#pragma unroll
      for (int r = 0; r < 4; r++) sreg[t][r] = s[r] * msk + off;
    }

    // ---- online softmax update (per row = quad*4+r) ----
    float cm[4];
#pragma unroll
    for (int r = 0; r < 4; r++) {
      float m = sreg[0][r];
#pragma unroll
      for (int t = 1; t < 8; t++) m = fmaxf(m, sreg[t][r]);
      m = fmaxf(m, __shfl_xor(m, 1));
      m = fmaxf(m, __shfl_xor(m, 2));
      m = fmaxf(m, __shfl_xor(m, 4));
      m = fmaxf(m, __shfl_xor(m, 8));
      cm[r] = m;
    }
    float alpha[4], rs[4];
#pragma unroll
    for (int r = 0; r < 4; r++) {
      float mnew = fmaxf(m_run[r], cm[r]);
      alpha[r] = __expf(m_run[r] - mnew);
      m_run[r] = mnew;
      rs[r] = 0.f;
    }
#pragma unroll
    for (int t = 0; t < 8; t++) {
#pragma unroll
      for (int r = 0; r < 4; r++) {
        float p = __expf(sreg[t][r] - m_run[r]);
        rs[r] += p;
        Ps[w][quad * 4 + r][t * 16 + col] = f2bf(p);
      }
    }
#pragma unroll
    for (int r = 0; r < 4; r++) {
      float s = rs[r];
      s += __shfl_xor(s, 1);
      s += __shfl_xor(s, 2);
      s += __shfl_xor(s, 4);
      s += __shfl_xor(s, 8);
      l_run[r] = l_run[r] * alpha[r] + s;
#pragma unroll
      for (int t = 0; t < 4; t++) oacc[t][r] *= alpha[r];
    }

    // ---- O += P V : 4 k-steps of 32, 4 d-tiles of 16 ----
#pragma unroll
    for (int s = 0; s < 4; s++) {
      bf16x8 pa = *(const bf16x8*)&Ps[w][col][s * 32 + quad * 8];
#pragma unroll
      for (int t = 0; t < 4; t++) {
        bf16x8 vb = *(const bf16x8*)&Vts[t * 16 + col][s * 32 + quad * 8];
        oacc[t] = __builtin_amdgcn_mfma_f32_16x16x32_bf16(pa, vb, oacc[t], 0, 0, 0);
      }
    }
    __syncthreads();
  }

  // ---- epilogue: O / l, store bf16 ----
  float inv[4];
#pragma unroll
  for (int r = 0; r < 4; r++) inv[r] = 1.0f / l_run[r];
#pragma unroll
  for (int t = 0; t < 4; t++) {
#pragma unroll
    for (int r = 0; r < 4; r++) {
      obuf[((size_t)bg * NQS + q0 + quad * 4 + r) * DI + h * DHD + t * 16 + col] =
          f2bf(oacc[t][r] * inv[r]);
    }
  }
}

// ---------------- out projection + scaled scatter-add ----------------
__global__ __launch_bounds__(256) void gemm_outproj(
    const u16* __restrict__ obuf, const float* __restrict__ wout,
    const int* __restrict__ qidx, const float* __restrict__ qscore,
    float* __restrict__ dout) {
  int bg = blockIdx.z, b = bg >> 2, g = bg & 3;
  int row0 = blockIdx.y * 64, col0 = blockIdx.x * 64;
  __shared__ float As[32][68], Bs[32][68];
  int tid = threadIdx.x;
  int lr = tid >> 2, ks = (tid & 3) * 8;
  int tx = tid & 15, ty = tid >> 4;
  float acc[4][4] = {};
  const u16* Ab = obuf + ((size_t)bg * NQS + row0 + lr) * DI + ks;
  const float* Bb = wout + (size_t)g * DM * DI + (size_t)(col0 + lr) * DI + ks;
  for (int k0 = 0; k0 < 512; k0 += 32) {
    uint4 ua = *(const uint4*)(Ab + k0);
    float4 b0 = *(const float4*)(Bb + k0);
    float4 b1 = *(const float4*)(Bb + k0 + 4);
    As[ks + 0][lr] = bf2f((u16)(ua.x & 0xffff)); As[ks + 1][lr] = bf2f((u16)(ua.x >> 16));
    As[ks + 2][lr] = bf2f((u16)(ua.y & 0xffff)); As[ks + 3][lr] = bf2f((u16)(ua.y >> 16));
    As[ks + 4][lr] = bf2f((u16)(ua.z & 0xffff)); As[ks + 5][lr] = bf2f((u16)(ua.z >> 16));
    As[ks + 6][lr] = bf2f((u16)(ua.w & 0xffff)); As[ks + 7][lr] = bf2f((u16)(ua.w >> 16));
    Bs[ks + 0][lr] = b0.x; Bs[ks + 1][lr] = b0.y; Bs[ks + 2][lr] = b0.z; Bs[ks + 3][lr] = b0.w;
    Bs[ks + 4][lr] = b1.x; Bs[ks + 5][lr] = b1.y; Bs[ks + 6][lr] = b1.z; Bs[ks + 7][lr] = b1.w;
    __syncthreads();
#pragma unroll 8
    for (int kk = 0; kk < 32; kk++) {
      float4 av = *(const float4*)&As[kk][ty * 4];
      float4 bv = *(const float4*)&Bs[kk][tx * 4];
      acc[0][0] += av.x * bv.x; acc[0][1] += av.x * bv.y; acc[0][2] += av.x * bv.z; acc[0][3] += av.x * bv.w;
      acc[1][0] += av.y * bv.x; acc[1][1] += av.y * bv.y; acc[1][2] += av.y * bv.z; acc[1][3] += av.y * bv.w;
      acc[2][0] += av.z * bv.x; acc[2][1] += av.z * bv.y; acc[2][2] += av.z * bv.z; acc[2][3] += av.z * bv.w;
      acc[3][0] += av.w * bv.x; acc[3][1] += av.w * bv.y; acc[3][2] += av.w * bv.z; acc[3][3] += av.w * bv.w;
    }
    __syncthreads();
  }
#pragma unroll
  for (int i = 0; i < 4; i++) {
    int rowg = row0 + ty * 4 + i;
    float sc = qscore[bg * NQS + rowg];
    int tok = qidx[bg * NQS + rowg];
    float* orow = dout + ((size_t)b * SEQ + tok) * DM + col0 + tx * 4;
    atomicAdd(&orow[0], acc[i][0] * sc);
    atomicAdd(&orow[1], acc[i][1] * sc);
    atomicAdd(&orow[2], acc[i][2] * sc);
    atomicAdd(&orow[3], acc[i][3] * sc);
  }
}

// ---------------- finalize: mean + null-token fill ----------------
__global__ __launch_bounds__(256) void finalize_kernel(
    float* __restrict__ dout, const float* __restrict__ counts,
    const float* __restrict__ null_token) {
  int qd = blockIdx.x * 256 + threadIdx.x;
  int row = qd >> 8;
  int c4 = qd & 255;
  float cnt = counts[row];
  float4* p = (float4*)dout + qd;
  if (cnt > 0.f) {
    float4 v = *p;
    float inv = 1.0f / cnt;
    v.x *= inv; v.y *= inv; v.z *= inv; v.w *= inv;
    *p = v;
  } else {
    *p = ((const float4*)null_token)[c4];
  }
}

extern "C" void kernel_launch(void* const* d_in, const int* in_sizes, int n_in,
                              void* d_out, int out_size, void* d_ws, size_t ws_size,
                              hipStream_t stream) {
  const float* x = (const float*)d_in[0];
  const float* wqr = (const float*)d_in[1];
  const float* wkvr = (const float*)d_in[2];
  const float* wq = (const float*)d_in[3];
  const float* wkv = (const float*)d_in[4];
  const float* wout = (const float*)d_in[5];
  const float* nullkv = (const float*)d_in[6];
  const float* nulltok = (const float*)d_in[7];
  float* out = (float*)d_out;
  char* ws = (char*)d_ws;
  // workspace layout (bytes)
  float* qlog = (float*)(ws + 0);                  // 256 KB
  float* kvlog = (float*)(ws + 262144);            // 256 KB
  int* qidx = (int*)(ws + 524288);                 // 64 KB
  int* kvidx = (int*)(ws + 589824);                // 32 KB
  float* qscore = (float*)(ws + 622592);           // 64 KB
  float* kvscore = (float*)(ws + 688128);          // 32 KB
  float* counts = (float*)(ws + 720896);           // 64 KB
  u16* qbuf = (u16*)(ws + 786432);                 // 16 MB  [16][1024][512]
  u16* kbuf = (u16*)(ws + 17563648);               // 8 MB   [16][512][512]
  u16* vtbuf = (u16*)(ws + 25952256);              // 8.13MB [16][8][64][520] (+4KB slack)
  u16* obuf = (u16*)(ws + 34476032);               // 16 MB  [16][1024][512]

  hipMemsetAsync(counts, 0, 65536, stream);
  hipMemsetAsync(out, 0, (size_t)NB * SEQ * DM * 4, stream);
  router_kernel<<<4096, 256, 0, stream>>>(x, wqr, wkvr, qlog, kvlog);
  topk_kernel<<<16, 256, 0, stream>>>(qlog, NQS, qidx, qscore, counts);
  topk_kernel<<<16, 256, 0, stream>>>(kvlog, NKS, kvidx, kvscore, nullptr);
  gemm_qproj<<<dim3(8, 16, 16), 256, 0, stream>>>(x, qidx, wq, qbuf);
  gemm_kvproj<<<dim3(16, 8, 16), 256, 0, stream>>>(x, kvidx, wkv, kvscore, kbuf, vtbuf);
  attn_mfma<<<dim3(16, 8, 16), 256, 0, stream>>>(qbuf, kbuf, vtbuf, nullkv, obuf);
  gemm_outproj<<<dim3(16, 16, 16), 256, 0, stream>>>(obuf, wout, qidx, qscore, out);
  finalize_kernel<<<16384, 256, 0, stream>>>(out, counts, nulltok);
}

// Round 3
// 463.229 us; speedup vs baseline: 3.5096x; 2.3701x over previous
//
#include <hip/hip_runtime.h>
#include <math.h>

#define NB 4
#define SEQ 4096
#define DM 1024
#define NG 4
#define DI 512
#define NQS 1024
#define NKS 512
#define NHD 8
#define DHD 64
#define VTS 520  // vtbuf row stride (513 cols used, padded)

typedef unsigned int u32;
typedef unsigned short u16;
typedef __bf16 bf16x8 __attribute__((ext_vector_type(8)));
typedef float f32x4 __attribute__((ext_vector_type(4)));

__device__ __forceinline__ float bf2f(u16 u) { return __uint_as_float(((u32)u) << 16); }
__device__ __forceinline__ u16 f2bf(float f) {
  u32 u = __float_as_uint(f);
  u32 r = (u + 0x7FFFu + ((u >> 16) & 1u)) >> 16;
  return (u16)r;
}

// ---------------- fp32 -> bf16 bulk convert ----------------
__global__ __launch_bounds__(256) void convert_bf16(const float* __restrict__ src,
                                                    u16* __restrict__ dst, int n4) {
  int i = blockIdx.x * 256 + threadIdx.x;
  if (i < n4) {
    float4 v = ((const float4*)src)[i];
    ushort4 o;
    o.x = f2bf(v.x); o.y = f2bf(v.y); o.z = f2bf(v.z); o.w = f2bf(v.w);
    ((ushort4*)dst)[i] = o;
  }
}

// ---------------- router: logits[b][g][n] for q and kv (fp32 — selection exactness) ----------------
__global__ __launch_bounds__(256) void router_kernel(
    const float* __restrict__ x, const float* __restrict__ wqr,
    const float* __restrict__ wkvr, float* __restrict__ qlog,
    float* __restrict__ kvlog) {
  __shared__ float wsm[8192];
  int tid = threadIdx.x;
  for (int k = tid; k < 8192; k += 256)
    wsm[k] = (k < 4096) ? wqr[k] : wkvr[k - 4096];
  __syncthreads();
  int widx = blockIdx.x * 4 + (tid >> 6);
  int lane = tid & 63;
  int b = widx >> 12, tok = widx & 4095;
  const float4* xr = (const float4*)(x + ((size_t)(b * SEQ + tok)) * DM);
  float4 xv[4];
#pragma unroll
  for (int i = 0; i < 4; i++) xv[i] = xr[i * 64 + lane];
  float accs[8];
#pragma unroll
  for (int r = 0; r < 8; r++) {
    const float4* wr = (const float4*)(wsm + r * 1024);
    float a = 0.f;
#pragma unroll
    for (int i = 0; i < 4; i++) {
      float4 w4 = wr[i * 64 + lane];
      a += xv[i].x * w4.x + xv[i].y * w4.y + xv[i].z * w4.z + xv[i].w * w4.w;
    }
    accs[r] = a;
  }
#pragma unroll
  for (int r = 0; r < 8; r++) {
    float a = accs[r];
#pragma unroll
    for (int off = 32; off >= 1; off >>= 1) a += __shfl_xor(a, off);
    if (lane == 0) {
      if (r < 4) qlog[((b << 2) | r) * SEQ + tok] = a;
      else kvlog[((b << 2) | (r - 4)) * SEQ + tok] = a;
    }
  }
}

// ---------------- top-k radix select per (b,g) ----------------
__global__ __launch_bounds__(256) void topk_kernel(
    const float* __restrict__ logits, int K, int* __restrict__ out_idx,
    float* __restrict__ out_score, float* __restrict__ counts) {
  __shared__ u32 keys[4096];
  __shared__ int eqlist[2048];
  __shared__ int scnt[4];
  __shared__ int s_gt, s_eq;
  int bg = blockIdx.x;
  int tid = threadIdx.x;
  const float* L = logits + bg * 4096;
  for (int e = tid; e < 4096; e += 256) {
    u32 u = __float_as_uint(L[e]);
    keys[e] = (u >> 31) ? ~u : (u | 0x80000000u);
  }
  if (tid == 0) { s_gt = 0; s_eq = 0; }
  __syncthreads();
  u32 prefix = 0;
  int remaining = K;
  for (int bit = 31; bit >= 0; --bit) {
    u32 want = prefix | (1u << bit);
    u32 mask = ~((1u << bit) - 1u);
    int c = 0;
    for (int e = tid; e < 4096; e += 256) c += ((keys[e] & mask) == want) ? 1 : 0;
#pragma unroll
    for (int off = 32; off >= 1; off >>= 1) c += __shfl_xor(c, off);
    if ((tid & 63) == 0) scnt[tid >> 6] = c;
    __syncthreads();
    int total = scnt[0] + scnt[1] + scnt[2] + scnt[3];
    if (total >= remaining) prefix = want;
    else remaining -= total;
    __syncthreads();
  }
  u32 T = prefix;
  for (int e = tid; e < 4096; e += 256) {
    u32 k = keys[e];
    if (k > T) {
      int pos = atomicAdd(&s_gt, 1);
      out_idx[bg * K + pos] = e;
      float v = L[e];
      out_score[bg * K + pos] = 1.0f / (1.0f + __expf(-v));
      if (counts) atomicAdd(&counts[(bg >> 2) * SEQ + e], 1.0f);
    } else if (k == T) {
      int p = atomicAdd(&s_eq, 1);
      if (p < 2048) eqlist[p] = e;
    }
  }
  __syncthreads();
  int gt = s_gt;
  int eq = min(s_eq, 2048);
  int need = K - gt;
  for (int i = tid; i < eq; i += 256) {
    int my = eqlist[i];
    int rank = 0;
    for (int j = 0; j < eq; j++) rank += (eqlist[j] < my) ? 1 : 0;
    if (rank < need) {
      int pos = gt + rank;
      out_idx[bg * K + pos] = my;
      float v = L[my];
      out_score[bg * K + pos] = 1.0f / (1.0f + __expf(-v));
      if (counts) atomicAdd(&counts[(bg >> 2) * SEQ + my], 1.0f);
    }
  }
}

// ---------------- shared MFMA GEMM core: 128x128 tile, BK=64, swizzled LDS ----------------
struct Ptr4 { const u16* p[4]; };

__device__ __forceinline__ void mfma_core(Ptr4 A, Ptr4 B, u16* Asm, u16* Bsm,
                                          int ktiles, int tid, f32x4 (&acc)[4][4]) {
  int w = tid >> 6, lane = tid & 63;
  int col = lane & 15, quad = lane >> 4;
  int wr = w >> 1, wc = w & 1;
  for (int kt = 0; kt < ktiles; kt++) {
#pragma unroll
    for (int r = 0; r < 4; r++) {
      char* ldsA = (char*)Asm + (r * 256 + w * 64) * 16;
      __builtin_amdgcn_global_load_lds(
          (const __attribute__((address_space(1))) void*)(A.p[r] + kt * 64),
          (__attribute__((address_space(3))) void*)ldsA, 16, 0, 0);
    }
#pragma unroll
    for (int r = 0; r < 4; r++) {
      char* ldsB = (char*)Bsm + (r * 256 + w * 64) * 16;
      __builtin_amdgcn_global_load_lds(
          (const __attribute__((address_space(1))) void*)(B.p[r] + kt * 64),
          (__attribute__((address_space(3))) void*)ldsB, 16, 0, 0);
    }
    __syncthreads();
#pragma unroll
    for (int k04 = 0; k04 < 8; k04 += 4) {
      bf16x8 af[4], bfr[4];
#pragma unroll
      for (int t = 0; t < 4; t++) {
        int rowa = wr * 64 + t * 16 + col;
        int sp = (quad + k04) ^ (col & 7);
        af[t] = *(const bf16x8*)((const char*)Asm + (rowa * 8 + sp) * 16);
        int rowb = wc * 64 + t * 16 + col;
        bfr[t] = *(const bf16x8*)((const char*)Bsm + (rowb * 8 + sp) * 16);
      }
#pragma unroll
      for (int t = 0; t < 4; t++)
#pragma unroll
        for (int u = 0; u < 4; u++)
          acc[t][u] = __builtin_amdgcn_mfma_f32_16x16x32_bf16(af[t], bfr[u], acc[t][u], 0, 0, 0);
    }
    __syncthreads();
  }
}

// ---------------- q projection: qbuf[bg][1024][512] = gather(xbf) @ wq^T ----------------
__global__ __launch_bounds__(256) void gemm_qproj(
    const u16* __restrict__ xbf, const int* __restrict__ qidx,
    const u16* __restrict__ wqbf, u16* __restrict__ qbuf) {
  int bg = blockIdx.z, b = bg >> 2, g = bg & 3;
  int row0 = blockIdx.y * 128, col0 = blockIdx.x * 128;
  __shared__ __align__(16) u16 Asm[8192], Bsm[8192];
  __shared__ int ridx[128];
  int tid = threadIdx.x;
  if (tid < 128) ridx[tid] = qidx[bg * NQS + row0 + tid];
  __syncthreads();
  Ptr4 A, B;
#pragma unroll
  for (int r = 0; r < 4; r++) {
    int G = r * 256 + tid;
    int row = G >> 3;
    int seg = (G & 7) ^ (row & 7);
    A.p[r] = xbf + ((size_t)b * SEQ + ridx[row]) * DM + seg * 8;
    B.p[r] = wqbf + ((size_t)g * DI + col0 + row) * DM + seg * 8;
  }
  f32x4 acc[4][4] = {};
  mfma_core(A, B, Asm, Bsm, DM / 64, tid, acc);
  int w = tid >> 6, lane = tid & 63;
  int col = lane & 15, quad = lane >> 4;
  int wr = w >> 1, wc = w & 1;
#pragma unroll
  for (int t = 0; t < 4; t++)
#pragma unroll
    for (int u = 0; u < 4; u++)
#pragma unroll
      for (int r = 0; r < 4; r++) {
        int rowg = row0 + wr * 64 + t * 16 + quad * 4 + r;
        int colg = col0 + wc * 64 + u * 16 + col;
        qbuf[((size_t)bg * NQS + rowg) * DI + colg] = f2bf(acc[t][u][r]);
      }
}

// ---------------- kv projection: K -> kbuf, V^T (scaled) -> vtbuf ----------------
__global__ __launch_bounds__(256) void gemm_kvproj(
    const u16* __restrict__ xbf, const int* __restrict__ kvidx,
    const u16* __restrict__ wkvbf, const float* __restrict__ kvscore,
    u16* __restrict__ kbuf, u16* __restrict__ vtbuf) {
  int bg = blockIdx.z, b = bg >> 2, g = bg & 3;
  int row0 = blockIdx.y * 128, col0 = blockIdx.x * 128;
  __shared__ __align__(16) u16 Asm[8192], Bsm[8192];
  __shared__ int ridx[128];
  int tid = threadIdx.x;
  if (tid < 128) ridx[tid] = kvidx[bg * NKS + row0 + tid];
  __syncthreads();
  Ptr4 A, B;
#pragma unroll
  for (int r = 0; r < 4; r++) {
    int G = r * 256 + tid;
    int row = G >> 3;
    int seg = (G & 7) ^ (row & 7);
    A.p[r] = xbf + ((size_t)b * SEQ + ridx[row]) * DM + seg * 8;
    B.p[r] = wkvbf + ((size_t)g * (2 * DI) + col0 + row) * DM + seg * 8;
  }
  f32x4 acc[4][4] = {};
  mfma_core(A, B, Asm, Bsm, DM / 64, tid, acc);
  int w = tid >> 6, lane = tid & 63;
  int col = lane & 15, quad = lane >> 4;
  int wr = w >> 1, wc = w & 1;
  if (col0 < DI) {
#pragma unroll
    for (int t = 0; t < 4; t++)
#pragma unroll
      for (int u = 0; u < 4; u++)
#pragma unroll
        for (int r = 0; r < 4; r++) {
          int rowg = row0 + wr * 64 + t * 16 + quad * 4 + r;
          int colg = col0 + wc * 64 + u * 16 + col;
          kbuf[((size_t)bg * NKS + rowg) * DI + colg] = f2bf(acc[t][u][r]);
        }
  } else {
#pragma unroll
    for (int t = 0; t < 4; t++)
#pragma unroll
      for (int r = 0; r < 4; r++) {
        int rowg = row0 + wr * 64 + t * 16 + quad * 4 + r;
        float sc = kvscore[bg * NKS + rowg];
#pragma unroll
        for (int u = 0; u < 4; u++) {
          int vc = col0 - DI + wc * 64 + u * 16 + col;  // 0..511
          int h = vc >> 6, d = vc & 63;
          vtbuf[(((size_t)bg * NHD + h) * DHD + d) * VTS + rowg + 1] =
              f2bf(acc[t][u][r] * sc);
        }
      }
  }
}

// ---------------- out projection + scaled scatter-add ----------------
__global__ __launch_bounds__(256) void gemm_outproj(
    const u16* __restrict__ obuf, const u16* __restrict__ woutbf,
    const int* __restrict__ qidx, const float* __restrict__ qscore,
    float* __restrict__ dout) {
  int bg = blockIdx.z, b = bg >> 2, g = bg & 3;
  int row0 = blockIdx.y * 128, col0 = blockIdx.x * 128;
  __shared__ __align__(16) u16 Asm[8192], Bsm[8192];
  int tid = threadIdx.x;
  Ptr4 A, B;
#pragma unroll
  for (int r = 0; r < 4; r++) {
    int G = r * 256 + tid;
    int row = G >> 3;
    int seg = (G & 7) ^ (row & 7);
    A.p[r] = obuf + ((size_t)bg * NQS + row0 + row) * DI + seg * 8;
    B.p[r] = woutbf + ((size_t)g * DM + col0 + row) * DI + seg * 8;
  }
  f32x4 acc[4][4] = {};
  mfma_core(A, B, Asm, Bsm, DI / 64, tid, acc);
  int w = tid >> 6, lane = tid & 63;
  int col = lane & 15, quad = lane >> 4;
  int wr = w >> 1, wc = w & 1;
#pragma unroll
  for (int t = 0; t < 4; t++)
#pragma unroll
    for (int r = 0; r < 4; r++) {
      int rowg = row0 + wr * 64 + t * 16 + quad * 4 + r;
      float sc = qscore[bg * NQS + rowg];
      int tok = qidx[bg * NQS + rowg];
      float* orow = dout + ((size_t)b * SEQ + tok) * DM;
#pragma unroll
      for (int u = 0; u < 4; u++) {
        int colg = col0 + wc * 64 + u * 16 + col;
        atomicAdd(&orow[colg], acc[t][u][r] * sc);
      }
    }
}

// ---------------- MFMA flash attention (unchanged from round 2) ----------------
__global__ __launch_bounds__(256) void attn_mfma(
    const u16* __restrict__ qbuf, const u16* __restrict__ kbuf,
    const u16* __restrict__ vtbuf, const float* __restrict__ null_kv,
    u16* __restrict__ obuf) {
  int qt = blockIdx.x;
  int h = blockIdx.y;
  int bg = blockIdx.z;
  int g = bg & 3;
  int tid = threadIdx.x;
  int w = tid >> 6, lane = tid & 63;
  int col = lane & 15, quad = lane >> 4;

  __shared__ u16 Ks[128][72];
  __shared__ u16 Vts[64][136];
  __shared__ u16 Ps[4][16][136];

  int q0 = qt * 64 + w * 16;
  const u16* qp = qbuf + ((size_t)bg * NQS + q0 + col) * DI + h * DHD + quad * 8;
  bf16x8 qa0 = *(const bf16x8*)qp;
  bf16x8 qa1 = *(const bf16x8*)(qp + 32);

  f32x4 oacc[4] = {};
  float m_run[4], l_run[4];
#pragma unroll
  for (int r = 0; r < 4; r++) { m_run[r] = -3.0e38f; l_run[r] = 0.f; }

  for (int c = 0; c < 5; c++) {
    int base = c * 128;
    {
      int r = tid >> 1, half = tid & 1;
      int j = base + r;
      uint4* dst = (uint4*)&Ks[r][half * 32];
      if (j >= 1 && j <= 512) {
        const uint4* src = (const uint4*)(kbuf + ((size_t)bg * NKS + (j - 1)) * DI + h * DHD + half * 32);
        dst[0] = src[0]; dst[1] = src[1]; dst[2] = src[2]; dst[3] = src[3];
      } else if (j == 0) {
        const float* nk = null_kv + ((0 * NG + g) * NHD + h) * DHD + half * 32;
#pragma unroll
        for (int i = 0; i < 32; i++) Ks[0][half * 32 + i] = f2bf(nk[i]);
      } else {
        uint4 z = {0, 0, 0, 0};
        dst[0] = z; dst[1] = z; dst[2] = z; dst[3] = z;
      }
    }
    {
      int d = tid >> 2, seg = tid & 3;
      const uint4* src = (const uint4*)(vtbuf + (((size_t)bg * NHD + h) * DHD + d) * VTS + base + seg * 32);
      uint4* dst = (uint4*)&Vts[d][seg * 32];
      dst[0] = src[0]; dst[1] = src[1]; dst[2] = src[2]; dst[3] = src[3];
      if (c == 0 && seg == 0)
        Vts[d][0] = f2bf(null_kv[((1 * NG + g) * NHD + h) * DHD + d]);
    }
    __syncthreads();

    float sreg[8][4];
#pragma unroll
    for (int t = 0; t < 8; t++) {
      bf16x8 kb0 = *(const bf16x8*)&Ks[t * 16 + col][quad * 8];
      bf16x8 kb1 = *(const bf16x8*)&Ks[t * 16 + col][quad * 8 + 32];
      f32x4 s = {0.f, 0.f, 0.f, 0.f};
      s = __builtin_amdgcn_mfma_f32_16x16x32_bf16(qa0, kb0, s, 0, 0, 0);
      s = __builtin_amdgcn_mfma_f32_16x16x32_bf16(qa1, kb1, s, 0, 0, 0);
      int jg = base + t * 16 + col;
      float msk = (jg < 513) ? 0.125f : 0.f;
      float off = (jg < 513) ? 0.f : -3.0e38f;
#pragma unroll
      for (int r = 0; r < 4; r++) sreg[t][r] = s[r] * msk + off;
    }

    float cm[4];
#pragma unroll
    for (int r = 0; r < 4; r++) {
      float m = sreg[0][r];
#pragma unroll
      for (int t = 1; t < 8; t++) m = fmaxf(m, sreg[t][r]);
      m = fmaxf(m, __shfl_xor(m, 1));
      m = fmaxf(m, __shfl_xor(m, 2));
      m = fmaxf(m, __shfl_xor(m, 4));
      m = fmaxf(m, __shfl_xor(m, 8));
      cm[r] = m;
    }
    float alpha[4], rs[4];
#pragma unroll
    for (int r = 0; r < 4; r++) {
      float mnew = fmaxf(m_run[r], cm[r]);
      alpha[r] = __expf(m_run[r] - mnew);
      m_run[r] = mnew;
      rs[r] = 0.f;
    }
#pragma unroll
    for (int t = 0; t < 8; t++) {
#pragma unroll
      for (int r = 0; r < 4; r++) {
        float p = __expf(sreg[t][r] - m_run[r]);
        rs[r] += p;
        Ps[w][quad * 4 + r][t * 16 + col] = f2bf(p);
      }
    }
#pragma unroll
    for (int r = 0; r < 4; r++) {
      float s = rs[r];
      s += __shfl_xor(s, 1);
      s += __shfl_xor(s, 2);
      s += __shfl_xor(s, 4);
      s += __shfl_xor(s, 8);
      l_run[r] = l_run[r] * alpha[r] + s;
#pragma unroll
      for (int t = 0; t < 4; t++) oacc[t][r] *= alpha[r];
    }

#pragma unroll
    for (int s = 0; s < 4; s++) {
      bf16x8 pa = *(const bf16x8*)&Ps[w][col][s * 32 + quad * 8];
#pragma unroll
      for (int t = 0; t < 4; t++) {
        bf16x8 vb = *(const bf16x8*)&Vts[t * 16 + col][s * 32 + quad * 8];
        oacc[t] = __builtin_amdgcn_mfma_f32_16x16x32_bf16(pa, vb, oacc[t], 0, 0, 0);
      }
    }
    __syncthreads();
  }

  float inv[4];
#pragma unroll
  for (int r = 0; r < 4; r++) inv[r] = 1.0f / l_run[r];
#pragma unroll
  for (int t = 0; t < 4; t++) {
#pragma unroll
    for (int r = 0; r < 4; r++) {
      obuf[((size_t)bg * NQS + q0 + quad * 4 + r) * DI + h * DHD + t * 16 + col] =
          f2bf(oacc[t][r] * inv[r]);
    }
  }
}

// ---------------- finalize: mean + null-token fill ----------------
__global__ __launch_bounds__(256) void finalize_kernel(
    float* __restrict__ dout, const float* __restrict__ counts,
    const float* __restrict__ null_token) {
  int qd = blockIdx.x * 256 + threadIdx.x;
  int row = qd >> 8;
  int c4 = qd & 255;
  float cnt = counts[row];
  float4* p = (float4*)dout + qd;
  if (cnt > 0.f) {
    float4 v = *p;
    float inv = 1.0f / cnt;
    v.x *= inv; v.y *= inv; v.z *= inv; v.w *= inv;
    *p = v;
  } else {
    *p = ((const float4*)null_token)[c4];
  }
}

extern "C" void kernel_launch(void* const* d_in, const int* in_sizes, int n_in,
                              void* d_out, int out_size, void* d_ws, size_t ws_size,
                              hipStream_t stream) {
  const float* x = (const float*)d_in[0];
  const float* wqr = (const float*)d_in[1];
  const float* wkvr = (const float*)d_in[2];
  const float* wq = (const float*)d_in[3];
  const float* wkv = (const float*)d_in[4];
  const float* wout = (const float*)d_in[5];
  const float* nullkv = (const float*)d_in[6];
  const float* nulltok = (const float*)d_in[7];
  float* out = (float*)d_out;
  char* ws = (char*)d_ws;
  // workspace layout (bytes)
  float* qlog = (float*)(ws + 0);                  // 256 KB
  float* kvlog = (float*)(ws + 262144);            // 256 KB
  int* qidx = (int*)(ws + 524288);                 // 64 KB
  int* kvidx = (int*)(ws + 589824);                // 32 KB
  float* qscore = (float*)(ws + 622592);           // 64 KB
  float* kvscore = (float*)(ws + 688128);          // 32 KB
  float* counts = (float*)(ws + 720896);           // 64 KB
  u16* qbuf = (u16*)(ws + 786432);                 // 16 MB  [16][1024][512]
  u16* kbuf = (u16*)(ws + 17563648);               // 8 MB   [16][512][512]
  u16* vtbuf = (u16*)(ws + 25952256);              // 8.13MB [16][8][64][520]
  u16* obuf = (u16*)(ws + 34476032);               // 16 MB  [16][1024][512]
  u16* xbf = (u16*)(ws + 51253248);                // 32 MB  [4][4096][1024]
  u16* wqbf = (u16*)(ws + 84807680);               // 4 MB   [4][512][1024]
  u16* wkvbf = (u16*)(ws + 89001984);              // 8 MB   [4][1024][1024]
  u16* woutbf = (u16*)(ws + 97390592);             // 4 MB   [4][1024][512]
  // total ~101.6 MB

  hipMemsetAsync(counts, 0, 65536, stream);
  hipMemsetAsync(out, 0, (size_t)NB * SEQ * DM * 4, stream);
  convert_bf16<<<16384, 256, 0, stream>>>(x, xbf, 4194304);
  convert_bf16<<<2048, 256, 0, stream>>>(wq, wqbf, 524288);
  convert_bf16<<<4096, 256, 0, stream>>>(wkv, wkvbf, 1048576);
  convert_bf16<<<2048, 256, 0, stream>>>(wout, woutbf, 524288);
  router_kernel<<<4096, 256, 0, stream>>>(x, wqr, wkvr, qlog, kvlog);
  topk_kernel<<<16, 256, 0, stream>>>(qlog, NQS, qidx, qscore, counts);
  topk_kernel<<<16, 256, 0, stream>>>(kvlog, NKS, kvidx, kvscore, nullptr);
  gemm_qproj<<<dim3(4, 8, 16), 256, 0, stream>>>(xbf, qidx, wqbf, qbuf);
  gemm_kvproj<<<dim3(8, 4, 16), 256, 0, stream>>>(xbf, kvidx, wkvbf, kvscore, kbuf, vtbuf);
  attn_mfma<<<dim3(16, 8, 16), 256, 0, stream>>>(qbuf, kbuf, vtbuf, nullkv, obuf);
  gemm_outproj<<<dim3(8, 8, 16), 256, 0, stream>>>(obuf, woutbf, qidx, qscore, out);
  finalize_kernel<<<16384, 256, 0, stream>>>(out, counts, nulltok);
}